// Round 3
// baseline (87.036 us; speedup 1.0000x reference)
//
#include <hip/hip_runtime.h>
#include <hip/hip_bf16.h>

#define NS 2048          // speakers (= cols)
#define MU 16            // utterances
#define DD 256           // dim (= K)
#define NMROWS (NS*MU)   // 32768 rows
#define STRIPS 4
#define SC 512           // cols per strip
#define NSTEP 16         // 32-col steps per strip
#define BMROWS 256       // rows per main block (4 waves x 64 rows, M_rep=2)
#define THR 8.0f

typedef float  f32x4  __attribute__((ext_vector_type(4)));
typedef float  f32x16 __attribute__((ext_vector_type(16)));
typedef short  bf16x8 __attribute__((ext_vector_type(8)));
typedef unsigned short ushort8 __attribute__((ext_vector_type(8)));

#define LOG2E 1.44269504088896340736f
#define LN2   0.69314718055994530942f

#if __has_builtin(__builtin_amdgcn_exp2f)
#define EXP2F(x) __builtin_amdgcn_exp2f(x)
#else
#define EXP2F(x) exp2f(x)
#endif
#if __has_builtin(__builtin_amdgcn_logf)
#define LOG2F(x) __builtin_amdgcn_logf(x)   // v_log_f32 = log2
#else
#define LOG2F(x) __log2f(x)
#endif

__device__ __forceinline__ unsigned short f2bf(float x){
  unsigned u = __builtin_bit_cast(unsigned, x);
  u += 0x7fffu + ((u >> 16) & 1u);          // RNE
  return (unsigned short)(u >> 16);
}

// ---- fused prep: scaled bf16 centroids (k-major), bf16 embeddings (k-major),
// ---- exact-fp32 excluded-self diagonal; emb read ONCE ----
__launch_bounds__(256)
__global__ void prep_kernel(const float* __restrict__ emb,
                            const float* __restrict__ wp,
                            unsigned short* __restrict__ centk,
                            unsigned short* __restrict__ embk,   // may be null
                            float* __restrict__ diag2){
  __shared__ float E[16*260];    // 16 rows x 256 dims, pad stride 260
  __shared__ float sm[256];
  const int t = threadIdx.x;
  const int n = blockIdx.x;      // speaker
  const float* src = emb + (size_t)n*MU*DD;

  #pragma unroll
  for (int i=0;i<4;i++){
    int g = i*1024 + t*4;                 // coalesced f32x4
    f32x4 v = *(const f32x4*)(src + g);
    int m = g >> 8, d = g & 255;
    *(f32x4*)&E[m*260 + d] = v;
  }
  __syncthreads();

  {
    float s = 0.f;
    #pragma unroll
    for (int m=0;m<16;m++) s += E[m*260 + t];
    sm[t] = s;
  }
  __syncthreads();

  const float w2 = wp[0] * LOG2E;

  if (t < 32){                            // scaled centroid, bf16, k-major
    const float c16 = w2 * (1.0f/16.0f);
    ushort8 o;
    #pragma unroll
    for (int j=0;j<8;j++) o[j] = f2bf(sm[t*8+j]*c16);
    *(ushort8*)(centk + ((size_t)t*NS + n)*8) = o;
  }

  if (embk){                              // bf16 embeddings, k-major [kc][row][8]
    #pragma unroll
    for (int rep=0;rep<2;rep++){
      int idx = rep*256 + t;
      int m = idx & 15, kc = idx >> 4;
      ushort8 o;
      #pragma unroll
      for (int j=0;j<8;j++) o[j] = f2bf(E[m*260 + kc*8 + j]);
      *(ushort8*)(embk + ((size_t)kc*NMROWS + n*16 + m)*8) = o;
    }
  }

  {                                       // excluded-self diagonal (exact fp32)
    int m = t >> 4, j = t & 15;
    float acc = 0.f;
    #pragma unroll
    for (int i=0;i<16;i++){
      int d = j + 16*i;
      float e = E[m*260 + d];
      acc += e * (sm[d] - e);
    }
    acc += __shfl_xor(acc, 1, 16);
    acc += __shfl_xor(acc, 2, 16);
    acc += __shfl_xor(acc, 4, 16);
    acc += __shfl_xor(acc, 8, 16);
    if (j==0) diag2[n*16 + m] = acc * (w2 * (1.0f/15.0f));
  }
}

// ---- stage one 32-col B step-tile (16 KiB) via async global->LDS DMA ----
__device__ __forceinline__ void stage_b(const unsigned short* __restrict__ centk,
                                        unsigned short* lds0, int c0,
                                        int wave, int lane){
  #pragma unroll
  for (int i=0;i<4;i++){
    const int slot0 = (i*4 + wave)*64;                  // wave-uniform
    const int kc = (slot0 >> 5) + (lane >> 5);          // per-lane
    const unsigned short* g = centk + ((size_t)kc*NS + c0 + (lane & 31))*8;
    __builtin_amdgcn_global_load_lds(
        (const __attribute__((address_space(1))) void*)g,
        (__attribute__((address_space(3))) void*)(lds0 + (size_t)slot0*8),
        16, 0, 0);
  }
}

#define MFMA(a,b,c) __builtin_amdgcn_mfma_f32_32x32x16_bf16(a,b,c,0,0,0)

// ---- main: A in regs (2 rows/lane), B strip-tiles double-buffered in LDS ----
template<bool FROMF32>
__launch_bounds__(256,2)
__global__ void ge2e_main(const float* __restrict__ embf,
                          const unsigned short* __restrict__ embk,
                          const unsigned short* __restrict__ centk,
                          const float* __restrict__ diag2,
                          float2* __restrict__ msbuf){
  __shared__ ushort8 Bbuf[2][1024];   // 2 x 16 KiB

  const int tid  = threadIdx.x;
  const int lane = tid & 63;
  const int wave = tid >> 6;
  const int l31  = lane & 31, hi = lane >> 5;
  const int strip  = blockIdx.x & 3;
  const int rowBlk = blockIdx.x >> 2;
  const int c0 = strip * SC;
  const int row0w = rowBlk*BMROWS + wave*64;
  const int rowA = row0w + l31;
  const int rowB = rowA + 32;

  stage_b(centk, (unsigned short*)&Bbuf[0][0], c0, wave, lane);  // step 0

  bf16x8 af0[16], af1[16];
  if constexpr (FROMF32){
    const float* rp0 = embf + (size_t)rowA*DD;
    const float* rp1 = embf + (size_t)rowB*DD;
    #pragma unroll
    for (int st=0; st<16; ++st){
      int kc = 2*st + hi;
      f32x4 a0 = *(const f32x4*)(rp0 + kc*8);
      f32x4 a1 = *(const f32x4*)(rp0 + kc*8 + 4);
      f32x4 b0 = *(const f32x4*)(rp1 + kc*8);
      f32x4 b1 = *(const f32x4*)(rp1 + kc*8 + 4);
      bf16x8 oa, ob;
      #pragma unroll
      for (int j=0;j<4;j++){ oa[j]=(short)f2bf(a0[j]); oa[j+4]=(short)f2bf(a1[j]);
                             ob[j]=(short)f2bf(b0[j]); ob[j+4]=(short)f2bf(b1[j]); }
      af0[st]=oa; af1[st]=ob;
    }
  } else {
    #pragma unroll
    for (int st=0; st<16; ++st){
      int kc = 2*st + hi;
      af0[st] = *(const bf16x8*)(embk + ((size_t)kc*NMROWS + rowA)*8);
      af1[st] = *(const bf16x8*)(embk + ((size_t)kc*NMROWS + rowB)*8);
    }
  }

  const float dv0 = diag2[rowA], dv1 = diag2[rowB];
  const int lab0 = rowA >> 4, lab1 = rowB >> 4;
  const int labLocal = rowBlk*16 - c0;
  const bool hasdiag = (labLocal >= 0) && (labLocal < SC);
  const int dstep = (labLocal >> 5) & 15;

  float m0 = 0.f, s0 = 0.f, m1 = 0.f, s1 = 0.f;
  f32x16 mneg0, mneg1;
  #pragma unroll
  for (int i=0;i<16;i++){ mneg0[i]=0.f; mneg1[i]=0.f; }

  __syncthreads();   // A landed (via first-use waits), step-0 B staged

  for (int step=0; step<NSTEP; ++step){
    const int cb_ = step & 1;
    if (step+1 < NSTEP)
      stage_b(centk, (unsigned short*)&Bbuf[cb_^1][0], c0 + (step+1)*32, wave, lane);

    const ushort8* cur = &Bbuf[cb_][0];
    f32x16 acc0, acc1;
    {
      bf16x8 cb = *(const bf16x8*)&cur[hi*32 + l31];
      acc0 = MFMA(cb, af0[0], mneg0);      // C-init = -m folds the max subtract
      acc1 = MFMA(cb, af1[0], mneg1);
    }
    #pragma unroll
    for (int st=1; st<16; ++st){
      bf16x8 cb = *(const bf16x8*)&cur[(2*st+hi)*32 + l31];
      acc0 = MFMA(cb, af0[st], acc0);
      acc1 = MFMA(cb, af1[st], acc1);
    }

    if (hasdiag && step == dstep){        // block-uniform, one step only
      int colbase = c0 + step*32 + 4*hi;
      #pragma unroll
      for (int r=0;r<16;r++){
        int col = colbase + (r&3) + 8*(r>>2);
        if (col == lab0) acc0[r] = dv0 + mneg0[0];   // dv - m0
        if (col == lab1) acc1[r] = dv1 + mneg1[0];
      }
    }

    // per-frag tile max (acc = logit - m_running)
    float x0 = fmaxf(fmaxf(fmaxf(acc0[0],acc0[1]),fmaxf(acc0[2],acc0[3])),
                     fmaxf(fmaxf(acc0[4],acc0[5]),fmaxf(acc0[6],acc0[7])));
    float x1 = fmaxf(fmaxf(fmaxf(acc0[8],acc0[9]),fmaxf(acc0[10],acc0[11])),
                     fmaxf(fmaxf(acc0[12],acc0[13]),fmaxf(acc0[14],acc0[15])));
    float tm0 = fmaxf(x0, x1);
    float y0 = fmaxf(fmaxf(fmaxf(acc1[0],acc1[1]),fmaxf(acc1[2],acc1[3])),
                     fmaxf(fmaxf(acc1[4],acc1[5]),fmaxf(acc1[6],acc1[7])));
    float y1 = fmaxf(fmaxf(fmaxf(acc1[8],acc1[9]),fmaxf(acc1[10],acc1[11])),
                     fmaxf(fmaxf(acc1[12],acc1[13]),fmaxf(acc1[14],acc1[15])));
    float tm1 = fmaxf(y0, y1);

    if (__any(tm0 > THR) || __any(tm1 > THR)){   // rare rescale path
      float d0 = fmaxf(tm0, 0.f), d1 = fmaxf(tm1, 0.f);
      s0 *= EXP2F(-d0);  s1 *= EXP2F(-d1);
      m0 += d0;          m1 += d1;
      #pragma unroll
      for (int i=0;i<16;i++){ mneg0[i] = -m0; mneg1[i] = -m1; }
      float a0=0.f, a1=0.f;
      #pragma unroll
      for (int r=0;r<16;r++){ a0 += EXP2F(acc0[r]-d0); a1 += EXP2F(acc1[r]-d1); }
      s0 += a0; s1 += a1;
    } else {                                     // fast path: no subs at all
      float a0=0.f, a1=0.f;
      #pragma unroll
      for (int r=0;r<16;r++){ a0 += EXP2F(acc0[r]); a1 += EXP2F(acc1[r]); }
      s0 += a0; s1 += a1;
    }

    __syncthreads();   // drains own staging; next buffer ready, reads done
  }

  // merge hi-halves (same rows, disjoint 16-col interleave)
  float mo0 = __shfl_xor(m0,32,64), so0 = __shfl_xor(s0,32,64);
  float mm0 = fmaxf(m0,mo0);
  float ss0 = s0*EXP2F(m0-mm0) + so0*EXP2F(mo0-mm0);
  float mo1 = __shfl_xor(m1,32,64), so1 = __shfl_xor(s1,32,64);
  float mm1 = fmaxf(m1,mo1);
  float ss1 = s1*EXP2F(m1-mm1) + so1*EXP2F(mo1-mm1);

  if (hi==0){
    msbuf[(size_t)strip*NMROWS + rowA] = make_float2(mm0, ss0);
    msbuf[(size_t)strip*NMROWS + rowB] = make_float2(mm1, ss1);
  }
}

// ---- merge 4 strips per row -> per-row loss term -> per-block partial ----
__launch_bounds__(512)
__global__ void merge_kernel(const float2* __restrict__ msbuf,
                             const float* __restrict__ diag2,
                             float* __restrict__ partials){
  __shared__ float sh[8];
  const int row = blockIdx.x*512 + threadIdx.x;
  float2 p0 = msbuf[row];
  float2 p1 = msbuf[NMROWS + row];
  float2 p2 = msbuf[2*NMROWS + row];
  float2 p3 = msbuf[3*NMROWS + row];
  float mm = fmaxf(fmaxf(p0.x,p1.x), fmaxf(p2.x,p3.x));
  float ss = p0.y*EXP2F(p0.x-mm) + p1.y*EXP2F(p1.x-mm)
           + p2.y*EXP2F(p2.x-mm) + p3.y*EXP2F(p3.x-mm);
  float term = LN2*(mm + LOG2F(ss) - diag2[row]);
  #pragma unroll
  for (int off=32; off; off>>=1) term += __shfl_xor(term, off, 64);
  if ((threadIdx.x & 63)==0) sh[threadIdx.x>>6] = term;
  __syncthreads();
  if (threadIdx.x==0){
    float v = 0.f;
    #pragma unroll
    for (int i=0;i<8;i++) v += sh[i];
    partials[blockIdx.x] = v;
  }
}

__global__ void final_kernel(const float* __restrict__ partials,
                             float* __restrict__ out){
  int tid = threadIdx.x;              // 64
  float v = partials[tid];
  #pragma unroll
  for (int off=32; off; off>>=1) v += __shfl_xor(v, off, 64);
  if (tid==0) out[0] = v * (1.0f/NMROWS);
}

extern "C" void kernel_launch(void* const* d_in, const int* in_sizes, int n_in,
                              void* d_out, int out_size, void* d_ws, size_t ws_size,
                              hipStream_t stream){
  const float* emb = (const float*)d_in[0];
  const float* wp  = (const float*)d_in[1];
  // d_in[2] (b) cancels in the loss; unused.
  float* out = (float*)d_out;
  char* ws = (char*)d_ws;

  const size_t centk_b = (size_t)NS*DD*2;        // 1 MiB
  const size_t embk_b  = (size_t)NMROWS*DD*2;    // 16 MiB
  const size_t diag_b  = (size_t)NMROWS*4;       // 128 KiB
  const size_t ms_b    = (size_t)STRIPS*NMROWS*8;// 1 MiB
  const bool useEmbk = ws_size >= centk_b + embk_b + diag_b + ms_b + 1024;

  unsigned short* centk = (unsigned short*)ws;
  size_t off = centk_b;
  unsigned short* embk = useEmbk ? (unsigned short*)(ws + off) : nullptr;
  if (useEmbk) off += embk_b;
  float*  diag2 = (float*)(ws + off);  off += diag_b;
  float2* msbuf = (float2*)(ws + off); off += ms_b;
  float*  parts = (float*)(ws + off);

  prep_kernel<<<NS, 256, 0, stream>>>(emb, wp, centk, embk, diag2);
  if (useEmbk)
    ge2e_main<false><<<(NMROWS/BMROWS)*STRIPS, 256, 0, stream>>>(emb, embk, centk, diag2, msbuf);
  else
    ge2e_main<true><<<(NMROWS/BMROWS)*STRIPS, 256, 0, stream>>>(emb, embk, centk, diag2, msbuf);
  merge_kernel<<<NMROWS/512, 512, 0, stream>>>(msbuf, diag2, parts);
  final_kernel<<<1, 64, 0, stream>>>(parts, out);
}

// Round 4
// 62.326 us; speedup vs baseline: 1.3965x; 1.3965x over previous
//
#include <hip/hip_runtime.h>
#include <hip/hip_bf16.h>

#define NS 2048          // speakers (= cols)
#define MU 16            // utterances
#define DD 256           // dim (= K)
#define NMROWS (NS*MU)   // 32768 rows
#define STRIPS 4
#define SC 512           // cols per strip
#define NSTEP 16         // 32-col steps per strip
#define BMROWS 128       // rows per main block (4 waves x 32 rows, M_rep=1)
#define THR 8.0f

typedef float  f32x4  __attribute__((ext_vector_type(4)));
typedef float  f32x16 __attribute__((ext_vector_type(16)));
typedef short  bf16x8 __attribute__((ext_vector_type(8)));
typedef unsigned short ushort8 __attribute__((ext_vector_type(8)));

#define LOG2E 1.44269504088896340736f
#define LN2   0.69314718055994530942f

#if __has_builtin(__builtin_amdgcn_exp2f)
#define EXP2F(x) __builtin_amdgcn_exp2f(x)
#else
#define EXP2F(x) exp2f(x)
#endif
#if __has_builtin(__builtin_amdgcn_logf)
#define LOG2F(x) __builtin_amdgcn_logf(x)   // v_log_f32 = log2
#else
#define LOG2F(x) __log2f(x)
#endif

__device__ __forceinline__ unsigned short f2bf(float x){
  unsigned u = __builtin_bit_cast(unsigned, x);
  u += 0x7fffu + ((u >> 16) & 1u);          // RNE
  return (unsigned short)(u >> 16);
}

// ---- fused prep: scaled bf16 centroids (k-major), bf16 embeddings (k-major),
// ---- exact-fp32 excluded-self diagonal; emb read ONCE ----
__launch_bounds__(256)
__global__ void prep_kernel(const float* __restrict__ emb,
                            const float* __restrict__ wp,
                            unsigned short* __restrict__ centk,
                            unsigned short* __restrict__ embk,   // may be null
                            float* __restrict__ diag2){
  __shared__ float E[16*260];    // 16 rows x 256 dims, pad stride 260
  __shared__ float sm[256];
  const int t = threadIdx.x;
  const int n = blockIdx.x;      // speaker
  const float* src = emb + (size_t)n*MU*DD;

  #pragma unroll
  for (int i=0;i<4;i++){
    int g = i*1024 + t*4;                 // coalesced f32x4
    f32x4 v = *(const f32x4*)(src + g);
    int m = g >> 8, d = g & 255;
    *(f32x4*)&E[m*260 + d] = v;
  }
  __syncthreads();

  {
    float s = 0.f;
    #pragma unroll
    for (int m=0;m<16;m++) s += E[m*260 + t];
    sm[t] = s;
  }
  __syncthreads();

  const float w2 = wp[0] * LOG2E;

  if (t < 32){                            // scaled centroid, bf16, k-major
    const float c16 = w2 * (1.0f/16.0f);
    ushort8 o;
    #pragma unroll
    for (int j=0;j<8;j++) o[j] = f2bf(sm[t*8+j]*c16);
    *(ushort8*)(centk + ((size_t)t*NS + n)*8) = o;
  }

  if (embk){                              // bf16 embeddings, k-major [kc][row][8]
    #pragma unroll
    for (int rep=0;rep<2;rep++){
      int idx = rep*256 + t;
      int m = idx & 15, kc = idx >> 4;
      ushort8 o;
      #pragma unroll
      for (int j=0;j<8;j++) o[j] = f2bf(E[m*260 + kc*8 + j]);
      *(ushort8*)(embk + ((size_t)kc*NMROWS + n*16 + m)*8) = o;
    }
  }

  {                                       // excluded-self diagonal (exact fp32)
    int m = t >> 4, j = t & 15;
    float acc = 0.f;
    #pragma unroll
    for (int i=0;i<16;i++){
      int d = j + 16*i;
      float e = E[m*260 + d];
      acc += e * (sm[d] - e);
    }
    acc += __shfl_xor(acc, 1, 16);
    acc += __shfl_xor(acc, 2, 16);
    acc += __shfl_xor(acc, 4, 16);
    acc += __shfl_xor(acc, 8, 16);
    if (j==0) diag2[n*16 + m] = acc * (w2 * (1.0f/15.0f));
  }
}

// ---- stage one 32-col B step-tile (16 KiB) via async global->LDS DMA ----
// slot s = kc*32+col (16B each); wave covers 64 consecutive slots per round
__device__ __forceinline__ void stage_b(const unsigned short* __restrict__ centk,
                                        unsigned short* lds0, int c0,
                                        int wave, int lane){
  #pragma unroll
  for (int i=0;i<4;i++){
    const int s0 = i*256 + wave*64;                    // wave-uniform slot base
    const int kc = (s0 >> 5) + (lane >> 5);
    const unsigned short* g = centk + ((size_t)kc*NS + c0 + (lane & 31))*8;
    __builtin_amdgcn_global_load_lds(
        (const __attribute__((address_space(1))) void*)g,
        (__attribute__((address_space(3))) void*)(lds0 + (size_t)s0*8),
        16, 0, 0);
  }
}

#define MFMA(a,b,c) __builtin_amdgcn_mfma_f32_32x32x16_bf16(a,b,c,0,0,0)

// ---- main: A in regs (1 row/lane), 32-col B steps double-buffered in LDS ----
template<bool FROMF32>
__launch_bounds__(256,4)
__global__ void ge2e_main(const float* __restrict__ embf,
                          const unsigned short* __restrict__ embk,
                          const unsigned short* __restrict__ centk,
                          const float* __restrict__ diag2,
                          float2* __restrict__ msbuf){
  __shared__ ushort8 Bbuf[2][1024];   // 2 x 16 KiB

  const int tid  = threadIdx.x;
  const int lane = tid & 63;
  const int wave = tid >> 6;
  const int l31  = lane & 31, hi = lane >> 5;
  const int strip  = blockIdx.x & 3;
  const int rowBlk = blockIdx.x >> 2;
  const int c0 = strip * SC;
  const int rowA = rowBlk*BMROWS + wave*32 + l31;   // this lane's (only) row

  stage_b(centk, (unsigned short*)&Bbuf[0][0], c0, wave, lane);  // step 0

  bf16x8 af[16];
  if constexpr (FROMF32){
    const float* rp = embf + (size_t)rowA*DD;
    #pragma unroll
    for (int st=0; st<16; ++st){
      int kc = 2*st + hi;
      f32x4 v0 = *(const f32x4*)(rp + kc*8);
      f32x4 v1 = *(const f32x4*)(rp + kc*8 + 4);
      bf16x8 o;
      #pragma unroll
      for (int j=0;j<4;j++){ o[j]=(short)f2bf(v0[j]); o[j+4]=(short)f2bf(v1[j]); }
      af[st] = o;
    }
  } else {
    #pragma unroll
    for (int st=0; st<16; ++st)
      af[st] = *(const bf16x8*)(embk + ((size_t)(2*st+hi)*NMROWS + rowA)*8);
  }

  const float dv  = diag2[rowA];
  const int   lab = rowA >> 4;
  const int   labc0 = rowBlk*8;                      // 8 label-cols of this block
  const bool  hasdiag = (labc0 >= c0) && (labc0 < c0 + SC);
  const int   dstep = (labc0 - c0) >> 5;             // valid only if hasdiag

  float m = -3.0e38f, s = 0.f;

  __syncthreads();   // step-0 staging (all waves) drained: full vmcnt(0) here

  for (int step=0; step<NSTEP; ++step){
    const int cb_ = step & 1;
    if (step+1 < NSTEP)
      stage_b(centk, (unsigned short*)&Bbuf[cb_^1][0], c0 + (step+1)*32, wave, lane);

    const ushort8* cur = &Bbuf[cb_][0];
    f32x16 acc;
    #pragma unroll
    for (int i=0;i<16;i++) acc[i] = 0.f;

    #pragma unroll
    for (int st=0; st<16; ++st){
      bf16x8 cb = *(const bf16x8*)&cur[(2*st+hi)*32 + l31];
      acc = MFMA(cb, af[st], acc);
    }

    if (hasdiag && step == dstep){        // block-uniform, one step only
      int colbase = c0 + step*32 + 4*hi;
      #pragma unroll
      for (int r=0;r<16;r++){
        int col = colbase + (r&3) + 8*(r>>2);
        if (col == lab) acc[r] = dv;
      }
    }

    // online softmax (log2 domain), lane-local, defer-max (THR=8)
    float x0 = fmaxf(fmaxf(fmaxf(acc[0],acc[1]),fmaxf(acc[2],acc[3])),
                     fmaxf(fmaxf(acc[4],acc[5]),fmaxf(acc[6],acc[7])));
    float x1 = fmaxf(fmaxf(fmaxf(acc[8],acc[9]),fmaxf(acc[10],acc[11])),
                     fmaxf(fmaxf(acc[12],acc[13]),fmaxf(acc[14],acc[15])));
    float tm = fmaxf(x0, x1);
    if (__any(tm > m + THR)){             // rare after step 0
      float mn = fmaxf(m, tm);
      s *= EXP2F(m - mn);
      m = mn;
    }
    float a0 = EXP2F(acc[0]-m)+EXP2F(acc[1]-m)+EXP2F(acc[2]-m)+EXP2F(acc[3]-m);
    float a1 = EXP2F(acc[4]-m)+EXP2F(acc[5]-m)+EXP2F(acc[6]-m)+EXP2F(acc[7]-m);
    float a2 = EXP2F(acc[8]-m)+EXP2F(acc[9]-m)+EXP2F(acc[10]-m)+EXP2F(acc[11]-m);
    float a3 = EXP2F(acc[12]-m)+EXP2F(acc[13]-m)+EXP2F(acc[14]-m)+EXP2F(acc[15]-m);
    s += (a0+a1)+(a2+a3);

    asm volatile("s_waitcnt vmcnt(0)" ::: "memory");  // own prefetch landed
    __builtin_amdgcn_s_barrier();                     // all reads of cur done
  }

  // merge hi-halves (same row, disjoint 16-col interleave per step)
  float mo = __shfl_xor(m,32,64), so = __shfl_xor(s,32,64);
  float mm = fmaxf(m,mo);
  float ss = s*EXP2F(m-mm) + so*EXP2F(mo-mm);

  if (hi==0) msbuf[(size_t)strip*NMROWS + rowA] = make_float2(mm, ss);
}

// ---- merge 4 strips per row -> per-row loss term -> per-block partial ----
__launch_bounds__(512)
__global__ void merge_kernel(const float2* __restrict__ msbuf,
                             const float* __restrict__ diag2,
                             float* __restrict__ partials){
  __shared__ float sh[8];
  const int row = blockIdx.x*512 + threadIdx.x;
  float2 p0 = msbuf[row];
  float2 p1 = msbuf[NMROWS + row];
  float2 p2 = msbuf[2*NMROWS + row];
  float2 p3 = msbuf[3*NMROWS + row];
  float mm = fmaxf(fmaxf(p0.x,p1.x), fmaxf(p2.x,p3.x));
  float ss = p0.y*EXP2F(p0.x-mm) + p1.y*EXP2F(p1.x-mm)
           + p2.y*EXP2F(p2.x-mm) + p3.y*EXP2F(p3.x-mm);
  float term = LN2*(mm + LOG2F(ss) - diag2[row]);
  #pragma unroll
  for (int off=32; off; off>>=1) term += __shfl_xor(term, off, 64);
  if ((threadIdx.x & 63)==0) sh[threadIdx.x>>6] = term;
  __syncthreads();
  if (threadIdx.x==0){
    float v = 0.f;
    #pragma unroll
    for (int i=0;i<8;i++) v += sh[i];
    partials[blockIdx.x] = v;
  }
}

__global__ void final_kernel(const float* __restrict__ partials,
                             float* __restrict__ out){
  int tid = threadIdx.x;              // 64
  float v = partials[tid];
  #pragma unroll
  for (int off=32; off; off>>=1) v += __shfl_xor(v, off, 64);
  if (tid==0) out[0] = v * (1.0f/NMROWS);
}

extern "C" void kernel_launch(void* const* d_in, const int* in_sizes, int n_in,
                              void* d_out, int out_size, void* d_ws, size_t ws_size,
                              hipStream_t stream){
  const float* emb = (const float*)d_in[0];
  const float* wp  = (const float*)d_in[1];
  // d_in[2] (b) cancels in the loss; unused.
  float* out = (float*)d_out;
  char* ws = (char*)d_ws;

  const size_t centk_b = (size_t)NS*DD*2;        // 1 MiB
  const size_t embk_b  = (size_t)NMROWS*DD*2;    // 16 MiB
  const size_t diag_b  = (size_t)NMROWS*4;       // 128 KiB
  const size_t ms_b    = (size_t)STRIPS*NMROWS*8;// 1 MiB
  const bool useEmbk = ws_size >= centk_b + embk_b + diag_b + ms_b + 1024;

  unsigned short* centk = (unsigned short*)ws;
  size_t off = centk_b;
  unsigned short* embk = useEmbk ? (unsigned short*)(ws + off) : nullptr;
  if (useEmbk) off += embk_b;
  float*  diag2 = (float*)(ws + off);  off += diag_b;
  float2* msbuf = (float2*)(ws + off); off += ms_b;
  float*  parts = (float*)(ws + off);

  prep_kernel<<<NS, 256, 0, stream>>>(emb, wp, centk, embk, diag2);
  if (useEmbk)
    ge2e_main<false><<<(NMROWS/BMROWS)*STRIPS, 256, 0, stream>>>(emb, embk, centk, diag2, msbuf);
  else
    ge2e_main<true><<<(NMROWS/BMROWS)*STRIPS, 256, 0, stream>>>(emb, embk, centk, diag2, msbuf);
  merge_kernel<<<NMROWS/512, 512, 0, stream>>>(msbuf, diag2, parts);
  final_kernel<<<1, 64, 0, stream>>>(parts, out);
}

// Round 5
// 47.646 us; speedup vs baseline: 1.8267x; 1.3081x over previous
//
#include <hip/hip_runtime.h>
#include <hip/hip_bf16.h>
#if !__has_builtin(__builtin_amdgcn_cvt_pk_fp8_f32)
#include <hip/hip_fp8.h>
#endif

#define NS 2048          // speakers (= cols)
#define MU 16            // utterances
#define DD 256           // dim (= K)
#define NMROWS (NS*MU)   // 32768 rows
#define STRIPS 8
#define SC 256           // cols per strip
#define NSTEP 8          // 32-col steps per strip
#define BMROWS 128       // rows per main block (4 waves x 32 rows)
#define THR 8.0f

typedef float  f32x4  __attribute__((ext_vector_type(4)));
typedef float  f32x16 __attribute__((ext_vector_type(16)));
typedef int    i32x4  __attribute__((ext_vector_type(4)));

#define LOG2E 1.44269504088896340736f
#define LN2   0.69314718055994530942f

#if __has_builtin(__builtin_amdgcn_exp2f)
#define EXP2F(x) __builtin_amdgcn_exp2f(x)
#else
#define EXP2F(x) exp2f(x)
#endif
#if __has_builtin(__builtin_amdgcn_logf)
#define LOG2F(x) __builtin_amdgcn_logf(x)   // v_log_f32 = log2
#else
#define LOG2F(x) __log2f(x)
#endif

// pack 4 f32 -> 4 fp8 e4m3 (RNE) in one dword
__device__ __forceinline__ int pk4(float a, float b, float c, float d){
#if __has_builtin(__builtin_amdgcn_cvt_pk_fp8_f32)
  int v = __builtin_amdgcn_cvt_pk_fp8_f32(a, b, 0, false);
  v = __builtin_amdgcn_cvt_pk_fp8_f32(c, d, v, true);
  return v;
#else
  unsigned r = (unsigned)__hip_fp8_e4m3(a).__x
             | ((unsigned)__hip_fp8_e4m3(b).__x << 8)
             | ((unsigned)__hip_fp8_e4m3(c).__x << 16)
             | ((unsigned)__hip_fp8_e4m3(d).__x << 24);
  return (int)r;
#endif
}
__device__ __forceinline__ long mk64(int lo, int hi){
  return (long)(((unsigned long long)(unsigned)lo) |
                ((unsigned long long)(unsigned)hi << 32));
}

// ---- fused prep: fp8 scaled centroids (k16-major), fp8 embeddings (k16-major),
// ---- exact-fp32 excluded-self diagonal; emb read ONCE ----
__launch_bounds__(256)
__global__ void prep_kernel(const float* __restrict__ emb,
                            const float* __restrict__ wp,
                            unsigned char* __restrict__ centk,
                            unsigned char* __restrict__ embk8,   // may be null
                            float* __restrict__ diag2){
  __shared__ float E[16*260];    // 16 rows x 256 dims, pad stride 260
  __shared__ float sm[256];
  const int t = threadIdx.x;
  const int n = blockIdx.x;      // speaker
  const float* src = emb + (size_t)n*MU*DD;

  #pragma unroll
  for (int i=0;i<4;i++){
    int g = i*1024 + t*4;                 // coalesced f32x4
    f32x4 v = *(const f32x4*)(src + g);
    int m = g >> 8, d = g & 255;
    *(f32x4*)&E[m*260 + d] = v;
  }
  __syncthreads();

  {
    float s = 0.f;
    #pragma unroll
    for (int m=0;m<16;m++) s += E[m*260 + t];
    sm[t] = s;
  }
  __syncthreads();

  const float w2 = wp[0] * LOG2E;

  if (t < 16){                            // scaled centroid, fp8, [st][n][16]
    const float c16 = w2 * (1.0f/16.0f);
    const float* p = &sm[t*16];
    i32x4 o;
    #pragma unroll
    for (int q=0;q<4;q++)
      o[q] = pk4(p[q*4]*c16, p[q*4+1]*c16, p[q*4+2]*c16, p[q*4+3]*c16);
    *(i32x4*)(centk + ((size_t)t*NS + n)*16) = o;
  }

  if (embk8){                             // fp8 embeddings, [st][row][16]
    int st = t >> 4, r = t & 15;
    const float* p = &E[r*260 + st*16];
    i32x4 o;
    #pragma unroll
    for (int q=0;q<4;q++){
      f32x4 v = *(const f32x4*)(p + q*4);
      o[q] = pk4(v[0], v[1], v[2], v[3]);
    }
    *(i32x4*)(embk8 + ((size_t)st*NMROWS + n*16 + r)*16) = o;
  }

  {                                       // excluded-self diagonal (exact fp32)
    int m = t >> 4, j = t & 15;
    float acc = 0.f;
    #pragma unroll
    for (int i=0;i<16;i++){
      int d = j + 16*i;
      float e = E[m*260 + d];
      acc += e * (sm[d] - e);
    }
    acc += __shfl_xor(acc, 1, 16);
    acc += __shfl_xor(acc, 2, 16);
    acc += __shfl_xor(acc, 4, 16);
    acc += __shfl_xor(acc, 8, 16);
    if (j==0) diag2[n*16 + m] = acc * (w2 * (1.0f/15.0f));
  }
}

// ---- stage one 32-col fp8 B step-tile (8 KiB) via async global->LDS DMA ----
// slot16 s = st*32+col (16B each, st = 16-elem k-chunk); 2 rounds of 256 thr
__device__ __forceinline__ void stage_b(const unsigned char* __restrict__ centk,
                                        long* lds0, int colbase,
                                        int wave, int lane){
  #pragma unroll
  for (int i=0;i<2;i++){
    const int s0 = (i*4 + wave)*64;                    // wave-uniform slot base
    const int st = (s0 >> 5) + (lane >> 5);
    const unsigned char* g = centk + ((size_t)st*NS + colbase + (lane & 31))*16;
    __builtin_amdgcn_global_load_lds(
        (const __attribute__((address_space(1))) void*)g,
        (__attribute__((address_space(3))) void*)((char*)lds0 + (size_t)s0*16),
        16, 0, 0);
  }
}

#define MFMA8(a,b,c) __builtin_amdgcn_mfma_f32_32x32x16_fp8_fp8(a,b,c,0,0,0)

// ---- main: fp8 A in regs (1 row/lane, 32 VGPR), fp8 B double-buffered in LDS ----
template<bool FROMF32>
__launch_bounds__(256,4)
__global__ void ge2e_main(const float* __restrict__ embf,
                          const unsigned char* __restrict__ embk8,
                          const unsigned char* __restrict__ centk,
                          const float* __restrict__ diag2,
                          float2* __restrict__ msbuf){
  __shared__ long Bbuf[2][1024];   // 2 x 8 KiB

  const int tid  = threadIdx.x;
  const int lane = tid & 63;
  const int wave = tid >> 6;
  const int l31  = lane & 31, hi = lane >> 5;
  const int strip  = blockIdx.x & 7;
  const int rowBlk = blockIdx.x >> 3;
  const int c0 = strip * SC;
  const int rowA = rowBlk*BMROWS + wave*32 + l31;   // this lane's (only) row

  stage_b(centk, &Bbuf[0][0], c0, wave, lane);      // step 0

  long af[16];
  if constexpr (FROMF32){
    const float* rp = embf + (size_t)rowA*DD;
    #pragma unroll
    for (int st=0; st<16; ++st){
      f32x4 v0 = *(const f32x4*)(rp + 16*st + 8*hi);
      f32x4 v1 = *(const f32x4*)(rp + 16*st + 8*hi + 4);
      af[st] = mk64(pk4(v0[0],v0[1],v0[2],v0[3]), pk4(v1[0],v1[1],v1[2],v1[3]));
    }
  } else {
    #pragma unroll
    for (int st=0; st<16; ++st)
      af[st] = *(const long*)(embk8 + ((size_t)st*NMROWS + rowA)*16 + hi*8);
  }

  const float dv  = diag2[rowA];
  const int   lab = rowA >> 4;
  const int   labc0 = rowBlk*8;                      // 8 label-cols of this block
  const bool  hasdiag = (labc0 >= c0) && (labc0 < c0 + SC);
  const int   dstep = (labc0 - c0) >> 5;             // valid only if hasdiag

  float m = -3.0e38f, s = 0.f;

  __syncthreads();   // step-0 staging (all waves) drained: full vmcnt(0) here

  for (int step=0; step<NSTEP; ++step){
    const int cb_ = step & 1;
    if (step+1 < NSTEP)
      stage_b(centk, &Bbuf[cb_^1][0], c0 + (step+1)*32, wave, lane);

    f32x16 acc;
    #pragma unroll
    for (int i=0;i<16;i++) acc[i] = 0.f;

    #pragma unroll
    for (int st=0; st<16; ++st){
      long cb = Bbuf[cb_][st*64 + l31*2 + hi];
      acc = MFMA8(cb, af[st], acc);
    }

    if (hasdiag && step == dstep){        // block-uniform, one step only
      int colbase = c0 + step*32 + 4*hi;
      #pragma unroll
      for (int r=0;r<16;r++){
        int col = colbase + (r&3) + 8*(r>>2);
        if (col == lab) acc[r] = dv;      // exact-fp32 self term
      }
    }

    // online softmax (log2 domain), lane-local, defer-max (THR=8)
    float x0 = fmaxf(fmaxf(fmaxf(acc[0],acc[1]),fmaxf(acc[2],acc[3])),
                     fmaxf(fmaxf(acc[4],acc[5]),fmaxf(acc[6],acc[7])));
    float x1 = fmaxf(fmaxf(fmaxf(acc[8],acc[9]),fmaxf(acc[10],acc[11])),
                     fmaxf(fmaxf(acc[12],acc[13]),fmaxf(acc[14],acc[15])));
    float tm = fmaxf(x0, x1);
    if (__any(tm > m + THR)){             // rare after step 0
      float mn = fmaxf(m, tm);
      s *= EXP2F(m - mn);
      m = mn;
    }
    float a0 = EXP2F(acc[0]-m)+EXP2F(acc[1]-m)+EXP2F(acc[2]-m)+EXP2F(acc[3]-m);
    float a1 = EXP2F(acc[4]-m)+EXP2F(acc[5]-m)+EXP2F(acc[6]-m)+EXP2F(acc[7]-m);
    float a2 = EXP2F(acc[8]-m)+EXP2F(acc[9]-m)+EXP2F(acc[10]-m)+EXP2F(acc[11]-m);
    float a3 = EXP2F(acc[12]-m)+EXP2F(acc[13]-m)+EXP2F(acc[14]-m)+EXP2F(acc[15]-m);
    s += (a0+a1)+(a2+a3);

    asm volatile("s_waitcnt vmcnt(0)" ::: "memory");  // own prefetch landed
    __builtin_amdgcn_s_barrier();                     // all reads of cur done
  }

  // merge hi-halves (same row, disjoint 16-col interleave per step)
  float mo = __shfl_xor(m,32,64), so = __shfl_xor(s,32,64);
  float mm = fmaxf(m,mo);
  float ss = s*EXP2F(m-mm) + so*EXP2F(mo-mm);

  if (hi==0) msbuf[(size_t)strip*NMROWS + rowA] = make_float2(mm, ss);
}

// ---- merge 8 strips per row -> per-row loss term -> per-block partial ----
__launch_bounds__(512)
__global__ void merge_kernel(const float2* __restrict__ msbuf,
                             const float* __restrict__ diag2,
                             float* __restrict__ partials){
  __shared__ float sh[8];
  const int row = blockIdx.x*512 + threadIdx.x;
  float2 p[STRIPS];
  #pragma unroll
  for (int k=0;k<STRIPS;k++) p[k] = msbuf[(size_t)k*NMROWS + row];
  float mm = p[0].x;
  #pragma unroll
  for (int k=1;k<STRIPS;k++) mm = fmaxf(mm, p[k].x);
  float ss = 0.f;
  #pragma unroll
  for (int k=0;k<STRIPS;k++) ss += p[k].y * EXP2F(p[k].x - mm);
  float term = LN2*(mm + LOG2F(ss) - diag2[row]);
  #pragma unroll
  for (int off=32; off; off>>=1) term += __shfl_xor(term, off, 64);
  if ((threadIdx.x & 63)==0) sh[threadIdx.x>>6] = term;
  __syncthreads();
  if (threadIdx.x==0){
    float v = 0.f;
    #pragma unroll
    for (int i=0;i<8;i++) v += sh[i];
    partials[blockIdx.x] = v;
  }
}

__global__ void final_kernel(const float* __restrict__ partials,
                             float* __restrict__ out){
  int tid = threadIdx.x;              // 64
  float v = partials[tid];
  #pragma unroll
  for (int off=32; off; off>>=1) v += __shfl_xor(v, off, 64);
  if (tid==0) out[0] = v * (1.0f/NMROWS);
}

extern "C" void kernel_launch(void* const* d_in, const int* in_sizes, int n_in,
                              void* d_out, int out_size, void* d_ws, size_t ws_size,
                              hipStream_t stream){
  const float* emb = (const float*)d_in[0];
  const float* wp  = (const float*)d_in[1];
  // d_in[2] (b) cancels in the loss; unused.
  float* out = (float*)d_out;
  char* ws = (char*)d_ws;

  const size_t centk_b = (size_t)NS*DD;            // 512 KiB (fp8)
  const size_t embk_b  = (size_t)NMROWS*DD;        // 8 MiB  (fp8)
  const size_t diag_b  = (size_t)NMROWS*4;         // 128 KiB
  const size_t ms_b    = (size_t)STRIPS*NMROWS*8;  // 2 MiB
  const bool useEmbk = ws_size >= centk_b + embk_b + diag_b + ms_b + 1024;

  unsigned char* centk = (unsigned char*)ws;
  size_t off = centk_b;
  unsigned char* embk8 = useEmbk ? (unsigned char*)(ws + off) : nullptr;
  if (useEmbk) off += embk_b;
  float*  diag2 = (float*)(ws + off);  off += diag_b;
  float2* msbuf = (float2*)(ws + off); off += ms_b;
  float*  parts = (float*)(ws + off);

  prep_kernel<<<NS, 256, 0, stream>>>(emb, wp, centk, embk8, diag2);
  if (useEmbk)
    ge2e_main<false><<<(NMROWS/BMROWS)*STRIPS, 256, 0, stream>>>(emb, embk8, centk, diag2, msbuf);
  else
    ge2e_main<true><<<(NMROWS/BMROWS)*STRIPS, 256, 0, stream>>>(emb, embk8, centk, diag2, msbuf);
  merge_kernel<<<NMROWS/512, 512, 0, stream>>>(msbuf, diag2, parts);
  final_kernel<<<1, 64, 0, stream>>>(parts, out);
}

// Round 6
// 47.348 us; speedup vs baseline: 1.8382x; 1.0063x over previous
//
#include <hip/hip_runtime.h>
#include <hip/hip_bf16.h>
#if !__has_builtin(__builtin_amdgcn_cvt_pk_fp8_f32)
#include <hip/hip_fp8.h>
#endif

#define NS 2048          // speakers (= cols)
#define MU 16            // utterances
#define DD 256           // dim (= K)
#define NMROWS (NS*MU)   // 32768 rows
#define STRIPS 8
#define SC 256           // cols per strip
#define NSTEP 4          // 64-col steps per strip
#define BMROWS 128       // rows per main block (4 waves x 32 rows)
#define THR 8.0f

typedef float  f32x4  __attribute__((ext_vector_type(4)));
typedef float  f32x16 __attribute__((ext_vector_type(16)));
typedef int    i32x4  __attribute__((ext_vector_type(4)));

#define LOG2E 1.44269504088896340736f
#define LN2   0.69314718055994530942f

#if __has_builtin(__builtin_amdgcn_exp2f)
#define EXP2F(x) __builtin_amdgcn_exp2f(x)
#else
#define EXP2F(x) exp2f(x)
#endif
#if __has_builtin(__builtin_amdgcn_logf)
#define LOG2F(x) __builtin_amdgcn_logf(x)   // v_log_f32 = log2
#else
#define LOG2F(x) __log2f(x)
#endif

// pack 4 f32 -> 4 fp8 e4m3 (RNE) in one dword
__device__ __forceinline__ int pk4(float a, float b, float c, float d){
#if __has_builtin(__builtin_amdgcn_cvt_pk_fp8_f32)
  int v = __builtin_amdgcn_cvt_pk_fp8_f32(a, b, 0, false);
  v = __builtin_amdgcn_cvt_pk_fp8_f32(c, d, v, true);
  return v;
#else
  unsigned r = (unsigned)__hip_fp8_e4m3(a).__x
             | ((unsigned)__hip_fp8_e4m3(b).__x << 8)
             | ((unsigned)__hip_fp8_e4m3(c).__x << 16)
             | ((unsigned)__hip_fp8_e4m3(d).__x << 24);
  return (int)r;
#endif
}
__device__ __forceinline__ long mk64(int lo, int hi){
  return (long)(((unsigned long long)(unsigned)lo) |
                ((unsigned long long)(unsigned)hi << 32));
}

// centk8 layout (8B units): G(st,cg,hi,c32) = ((st*64 + cg)*2 + hi)*32 + c32
//   st   = 16-elem k-chunk (0..15)
//   cg   = col>>5, c32 = col&31, hi = which 8-k half
// This global pre-swizzle makes lane-linear global_load_lds produce a
// conflict-free LDS layout for the wave's b64 fragment reads.

// ---- fused prep: fp8 scaled centroids (swizzled), fp8 embeddings (k16-major),
// ---- exact-fp32 excluded-self diagonal; emb read ONCE ----
__launch_bounds__(256)
__global__ void prep_kernel(const float* __restrict__ emb,
                            const float* __restrict__ wp,
                            long* __restrict__ centk8,
                            unsigned char* __restrict__ embk8,   // may be null
                            float* __restrict__ diag2){
  __shared__ float E[16*260];    // 16 rows x 256 dims, pad stride 260
  __shared__ float sm[256];
  const int t = threadIdx.x;
  const int n = blockIdx.x;      // speaker
  const float* src = emb + (size_t)n*MU*DD;

  #pragma unroll
  for (int i=0;i<4;i++){
    int g = i*1024 + t*4;                 // coalesced f32x4
    f32x4 v = *(const f32x4*)(src + g);
    int m = g >> 8, d = g & 255;
    *(f32x4*)&E[m*260 + d] = v;
  }
  __syncthreads();

  {
    float s = 0.f;
    #pragma unroll
    for (int m=0;m<16;m++) s += E[m*260 + t];
    sm[t] = s;
  }
  __syncthreads();

  const float w2 = wp[0] * LOG2E;

  if (t < 16){                            // scaled centroid, fp8, swizzled
    const float c16 = w2 * (1.0f/16.0f);
    const int st = t;
    const float* p = &sm[st*16];
    int q0 = pk4(p[0]*c16,  p[1]*c16,  p[2]*c16,  p[3]*c16);
    int q1 = pk4(p[4]*c16,  p[5]*c16,  p[6]*c16,  p[7]*c16);
    int q2 = pk4(p[8]*c16,  p[9]*c16,  p[10]*c16, p[11]*c16);
    int q3 = pk4(p[12]*c16, p[13]*c16, p[14]*c16, p[15]*c16);
    size_t base = ((size_t)(st*64 + (n>>5))*2)*32 + (n&31);
    centk8[base]      = mk64(q0, q1);     // hi=0 plane (k 0-7)
    centk8[base + 32] = mk64(q2, q3);     // hi=1 plane (k 8-15)
  }

  if (embk8){                             // fp8 embeddings, [st][row][16]
    int st = t >> 4, r = t & 15;
    const float* p = &E[r*260 + st*16];
    i32x4 o;
    #pragma unroll
    for (int q=0;q<4;q++){
      f32x4 v = *(const f32x4*)(p + q*4);
      o[q] = pk4(v[0], v[1], v[2], v[3]);
    }
    *(i32x4*)(embk8 + ((size_t)st*NMROWS + n*16 + r)*16) = o;
  }

  {                                       // excluded-self diagonal (exact fp32)
    int m = t >> 4, j = t & 15;
    float acc = 0.f;
    #pragma unroll
    for (int i=0;i<16;i++){
      int d = j + 16*i;
      float e = E[m*260 + d];
      acc += e * (sm[d] - e);
    }
    acc += __shfl_xor(acc, 1, 16);
    acc += __shfl_xor(acc, 2, 16);
    acc += __shfl_xor(acc, 4, 16);
    acc += __shfl_xor(acc, 8, 16);
    if (j==0) diag2[n*16 + m] = acc * (w2 * (1.0f/15.0f));
  }
}

// ---- stage one 64-col fp8 B step-tile (16 KiB) via async global->LDS DMA ----
// wave w, round i covers st = i*4+w: 64 lanes x 16B = the st's full 1 KiB row
__device__ __forceinline__ void stage_b(const long* __restrict__ centk8,
                                        long* lds0, int cg0,
                                        int wave, int lane){
  #pragma unroll
  for (int i=0;i<4;i++){
    const int st = i*4 + wave;
    const long* g = centk8 + (size_t)(st*64 + cg0)*64 + lane*2;
    __builtin_amdgcn_global_load_lds(
        (const __attribute__((address_space(1))) void*)g,
        (__attribute__((address_space(3))) void*)(lds0 + (size_t)st*128),
        16, 0, 0);
  }
}

#define MFMA8(a,b,c) __builtin_amdgcn_mfma_f32_32x32x16_fp8_fp8(a,b,c,0,0,0)

// ---- main: fp8 A in regs (1 row/lane), 64-col steps, 2 indep MFMA chains ----
template<bool FROMF32>
__launch_bounds__(256,4)
__global__ void ge2e_main(const float* __restrict__ embf,
                          const unsigned char* __restrict__ embk8,
                          const long* __restrict__ centk8,
                          const float* __restrict__ diag2,
                          float2* __restrict__ msbuf){
  __shared__ long Bbuf[2][2048];   // 2 x 16 KiB

  const int tid  = threadIdx.x;
  const int lane = tid & 63;
  const int wave = tid >> 6;
  const int l31  = lane & 31, hi = lane >> 5;
  const int strip  = blockIdx.x & 7;
  const int rowBlk = blockIdx.x >> 3;
  const int c0 = strip * SC;
  const int rowA = rowBlk*BMROWS + wave*32 + l31;   // this lane's (only) row

  stage_b(centk8, &Bbuf[0][0], c0 >> 5, wave, lane);   // step 0

  long af[16];
  if constexpr (FROMF32){
    const float* rp = embf + (size_t)rowA*DD;
    #pragma unroll
    for (int st=0; st<16; ++st){
      f32x4 v0 = *(const f32x4*)(rp + 16*st + 8*hi);
      f32x4 v1 = *(const f32x4*)(rp + 16*st + 8*hi + 4);
      af[st] = mk64(pk4(v0[0],v0[1],v0[2],v0[3]), pk4(v1[0],v1[1],v1[2],v1[3]));
    }
  } else {
    #pragma unroll
    for (int st=0; st<16; ++st)
      af[st] = *(const long*)(embk8 + ((size_t)st*NMROWS + rowA)*16 + hi*8);
  }

  const float dv  = diag2[rowA];
  const int   lab = rowA >> 4;
  const int   labc0 = rowBlk*8;                      // 8 label-cols of this block
  const bool  hasdiag = (labc0 >= c0) && (labc0 < c0 + SC);
  const int   dstep = (labc0 - c0) >> 6;             // valid only if hasdiag
  const int   dgrp  = ((labc0 - c0) >> 5) & 1;

  float m = 0.f, s = 0.f;

  __syncthreads();   // step-0 staging (all waves) drained: full vmcnt(0) here

  for (int step=0; step<NSTEP; ++step){
    const int cb_ = step & 1;
    if (step+1 < NSTEP)
      stage_b(centk8, &Bbuf[cb_^1][0], (c0 >> 5) + (step+1)*2, wave, lane);

    const long* cur = &Bbuf[cb_][0];
    const int bi = hi*32 + l31;          // conflict-free: 64 lanes = 512B dense

    f32x16 accA, accB;
    #pragma unroll
    for (int i=0;i<16;i++){ accA[i] = 0.f; accB[i] = 0.f; }

    #pragma unroll
    for (int st=0; st<16; ++st){         // two independent chains (2x ILP)
      long b0 = cur[st*128 + bi];
      long b1 = cur[st*128 + 64 + bi];
      accA = MFMA8(b0, af[st], accA);
      accB = MFMA8(b1, af[st], accB);
    }

    if (hasdiag && step == dstep){       // block-uniform, one step, one group
      int colbase = c0 + step*64 + dgrp*32 + 4*hi;
      if (dgrp == 0){
        #pragma unroll
        for (int r=0;r<16;r++){
          int col = colbase + (r&3) + 8*(r>>2);
          if (col == lab) accA[r] = dv;
        }
      } else {
        #pragma unroll
        for (int r=0;r<16;r++){
          int col = colbase + (r&3) + 8*(r>>2);
          if (col == lab) accB[r] = dv;
        }
      }
    }

    // online softmax (log2 domain), lane-local, defer-max (THR=8)
    float xa0 = fmaxf(fmaxf(fmaxf(accA[0],accA[1]),fmaxf(accA[2],accA[3])),
                      fmaxf(fmaxf(accA[4],accA[5]),fmaxf(accA[6],accA[7])));
    float xa1 = fmaxf(fmaxf(fmaxf(accA[8],accA[9]),fmaxf(accA[10],accA[11])),
                      fmaxf(fmaxf(accA[12],accA[13]),fmaxf(accA[14],accA[15])));
    float xb0 = fmaxf(fmaxf(fmaxf(accB[0],accB[1]),fmaxf(accB[2],accB[3])),
                      fmaxf(fmaxf(accB[4],accB[5]),fmaxf(accB[6],accB[7])));
    float xb1 = fmaxf(fmaxf(fmaxf(accB[8],accB[9]),fmaxf(accB[10],accB[11])),
                      fmaxf(fmaxf(accB[12],accB[13]),fmaxf(accB[14],accB[15])));
    float tm = fmaxf(fmaxf(xa0,xa1), fmaxf(xb0,xb1));
    if (__any(tm > m + THR)){            // triggers on early steps only
      float mn = fmaxf(m, tm);
      s *= EXP2F(m - mn);
      m = mn;
    }
    float a0 = EXP2F(accA[0]-m)+EXP2F(accA[1]-m)+EXP2F(accA[2]-m)+EXP2F(accA[3]-m);
    float a1 = EXP2F(accA[4]-m)+EXP2F(accA[5]-m)+EXP2F(accA[6]-m)+EXP2F(accA[7]-m);
    float a2 = EXP2F(accA[8]-m)+EXP2F(accA[9]-m)+EXP2F(accA[10]-m)+EXP2F(accA[11]-m);
    float a3 = EXP2F(accA[12]-m)+EXP2F(accA[13]-m)+EXP2F(accA[14]-m)+EXP2F(accA[15]-m);
    float b0 = EXP2F(accB[0]-m)+EXP2F(accB[1]-m)+EXP2F(accB[2]-m)+EXP2F(accB[3]-m);
    float b1 = EXP2F(accB[4]-m)+EXP2F(accB[5]-m)+EXP2F(accB[6]-m)+EXP2F(accB[7]-m);
    float b2 = EXP2F(accB[8]-m)+EXP2F(accB[9]-m)+EXP2F(accB[10]-m)+EXP2F(accB[11]-m);
    float b3 = EXP2F(accB[12]-m)+EXP2F(accB[13]-m)+EXP2F(accB[14]-m)+EXP2F(accB[15]-m);
    s += ((a0+a1)+(a2+a3)) + ((b0+b1)+(b2+b3));

    asm volatile("s_waitcnt vmcnt(0)" ::: "memory");  // own prefetch landed
    __builtin_amdgcn_s_barrier();                     // all reads of cur done
  }

  // merge hi-halves (same row, disjoint col subsets)
  float mo = __shfl_xor(m,32,64), so = __shfl_xor(s,32,64);
  float mm = fmaxf(m,mo);
  float ss = s*EXP2F(m-mm) + so*EXP2F(mo-mm);

  if (hi==0) msbuf[(size_t)strip*NMROWS + rowA] = make_float2(mm, ss);
}

// ---- merge 8 strips per row -> per-row loss term -> per-block partial ----
__launch_bounds__(512)
__global__ void merge_kernel(const float2* __restrict__ msbuf,
                             const float* __restrict__ diag2,
                             float* __restrict__ partials){
  __shared__ float sh[8];
  const int row = blockIdx.x*512 + threadIdx.x;
  float2 p[STRIPS];
  #pragma unroll
  for (int k=0;k<STRIPS;k++) p[k] = msbuf[(size_t)k*NMROWS + row];
  float mm = p[0].x;
  #pragma unroll
  for (int k=1;k<STRIPS;k++) mm = fmaxf(mm, p[k].x);
  float ss = 0.f;
  #pragma unroll
  for (int k=0;k<STRIPS;k++) ss += p[k].y * EXP2F(p[k].x - mm);
  float term = LN2*(mm + LOG2F(ss) - diag2[row]);
  #pragma unroll
  for (int off=32; off; off>>=1) term += __shfl_xor(term, off, 64);
  if ((threadIdx.x & 63)==0) sh[threadIdx.x>>6] = term;
  __syncthreads();
  if (threadIdx.x==0){
    float v = 0.f;
    #pragma unroll
    for (int i=0;i<8;i++) v += sh[i];
    partials[blockIdx.x] = v;
  }
}

__global__ void final_kernel(const float* __restrict__ partials,
                             float* __restrict__ out){
  int tid = threadIdx.x;              // 64
  float v = partials[tid];
  #pragma unroll
  for (int off=32; off; off>>=1) v += __shfl_xor(v, off, 64);
  if (tid==0) out[0] = v * (1.0f/NMROWS);
}

extern "C" void kernel_launch(void* const* d_in, const int* in_sizes, int n_in,
                              void* d_out, int out_size, void* d_ws, size_t ws_size,
                              hipStream_t stream){
  const float* emb = (const float*)d_in[0];
  const float* wp  = (const float*)d_in[1];
  // d_in[2] (b) cancels in the loss; unused.
  float* out = (float*)d_out;
  char* ws = (char*)d_ws;

  const size_t centk_b = (size_t)NS*DD;            // 512 KiB (fp8)
  const size_t embk_b  = (size_t)NMROWS*DD;        // 8 MiB  (fp8)
  const size_t diag_b  = (size_t)NMROWS*4;         // 128 KiB
  const size_t ms_b    = (size_t)STRIPS*NMROWS*8;  // 2 MiB
  const bool useEmbk = ws_size >= centk_b + embk_b + diag_b + ms_b + 1024;

  long* centk8 = (long*)ws;
  size_t off = centk_b;
  unsigned char* embk8 = useEmbk ? (unsigned char*)(ws + off) : nullptr;
  if (useEmbk) off += embk_b;
  float*  diag2 = (float*)(ws + off);  off += diag_b;
  float2* msbuf = (float2*)(ws + off); off += ms_b;
  float*  parts = (float*)(ws + off);

  prep_kernel<<<NS, 256, 0, stream>>>(emb, wp, centk8, embk8, diag2);
  if (useEmbk)
    ge2e_main<false><<<(NMROWS/BMROWS)*STRIPS, 256, 0, stream>>>(emb, embk8, centk8, diag2, msbuf);
  else
    ge2e_main<true><<<(NMROWS/BMROWS)*STRIPS, 256, 0, stream>>>(emb, embk8, centk8, diag2, msbuf);
  merge_kernel<<<NMROWS/512, 512, 0, stream>>>(msbuf, diag2, parts);
  final_kernel<<<1, 64, 0, stream>>>(parts, out);
}